// Round 6
// baseline (79.843 us; speedup 1.0000x reference)
//
#include <hip/hip_runtime.h>
#include <hip/hip_bf16.h>

#define S_LEN  1024
#define BATCH  4
#define DMODEL 1024
#define NHEAD  16
#define DHEAD  64
#define NROWS  (S_LEN*BATCH)   // 4096

typedef __bf16 bf16;
typedef __bf16 bf16x2 __attribute__((ext_vector_type(2)));
typedef __bf16 bf16x4 __attribute__((ext_vector_type(4)));
typedef __bf16 bf16x8 __attribute__((ext_vector_type(8)));
typedef float  f32x4  __attribute__((ext_vector_type(4)));

#define AS1 __attribute__((address_space(1)))
#define AS3 __attribute__((address_space(3)))

#define LOG2E   1.4426950408889634f
#define QSCALE  0.18033688011112042f   // 0.125 * log2(e)

__device__ __forceinline__ void gload16(const bf16* g, bf16* l) {
  __builtin_amdgcn_global_load_lds((const AS1 void*)g, (AS3 void*)l, 16, 0, 0);
}

__device__ __forceinline__ float fast_exp2(float x) {
#if __has_builtin(__builtin_amdgcn_exp2f)
  return __builtin_amdgcn_exp2f(x);
#else
  return exp2f(x);
#endif
}

// pack two f32 -> one dword of 2 bf16 (RNE via C casts; compiler may fuse to cvt_pk)
__device__ __forceinline__ int pack_bf16(float lo, float hi) {
  union { bf16x2 v; int i; } u;
  u.v[0] = (bf16)lo; u.v[1] = (bf16)hi;
  return u.i;
}

// ---------------- fused fp32 -> bf16 convert (hs + 3 weights, one launch) ----------------
__global__ __launch_bounds__(256) void cvt_all(
    const float* __restrict__ hs, const float* __restrict__ wq,
    const float* __restrict__ wk, const float* __restrict__ wv,
    bf16* __restrict__ Xb, bf16* __restrict__ Wb)
{
  const int b = blockIdx.x;
  const float* src; bf16* dst; int i;
  if (b < 2048)      { src = hs; dst = Xb;                           i = b*256        + threadIdx.x; }
  else if (b < 2560) { src = wq; dst = Wb;                           i = (b-2048)*256 + threadIdx.x; }
  else if (b < 3072) { src = wk; dst = Wb + (size_t)DMODEL*DMODEL;   i = (b-2560)*256 + threadIdx.x; }
  else               { src = wv; dst = Wb + (size_t)2*DMODEL*DMODEL; i = (b-3072)*256 + threadIdx.x; }
  const float4* s4 = (const float4*)src;
  float4 a = s4[2*i], c = s4[2*i+1];
  bf16x8 o;
  o[0]=(bf16)a.x; o[1]=(bf16)a.y; o[2]=(bf16)a.z; o[3]=(bf16)a.w;
  o[4]=(bf16)c.x; o[5]=(bf16)c.y; o[6]=(bf16)c.z; o[7]=(bf16)c.w;
  ((bf16x8*)dst)[i] = o;
}

// ---------------- fused QKV GEMM, m97 structure ----------------
#define BM 128
#define BN 128
#define BK 32

__global__ __launch_bounds__(256) void qkv_gemm(
    const bf16* __restrict__ X, const bf16* __restrict__ Wcat,
    const float* __restrict__ bq, const float* __restrict__ bk, const float* __restrict__ bv,
    bf16* __restrict__ Qo, bf16* __restrict__ Ko, bf16* __restrict__ Vo)
{
  __shared__ __align__(16) bf16 As[BM*BK];
  __shared__ __align__(16) bf16 Bs[BN*BK];

  const int tid  = threadIdx.x;
  const int row0 = blockIdx.x * BM;
  const int col0 = blockIdx.y * BN;
  const int wsel = col0 >> 10;
  const int coln = col0 & 1023;

  const int wv   = tid >> 6;
  const int lane = tid & 63;
  const int lg   = lane >> 4;
  const int lr   = lane & 15;
  const int wr   = (wv >> 1) << 6;
  const int wc   = (wv & 1) << 6;

  const int c0 = tid, c1 = tid + 256;
  const size_t gA0 = (size_t)(row0 + (c0>>2))*DMODEL + (size_t)((c0&3)<<3);
  const size_t gA1 = (size_t)(row0 + (c1>>2))*DMODEL + (size_t)((c1&3)<<3);
  const size_t gB0 = (size_t)(col0 + (c0>>2))*DMODEL + (size_t)((c0&3)<<3);
  const size_t gB1 = (size_t)(col0 + (c1>>2))*DMODEL + (size_t)((c1&3)<<3);
  const int wb = (tid >> 6) << 6;
  bf16* lA0 = As + (size_t)wb*8;
  bf16* lA1 = As + (size_t)(wb+256)*8;
  bf16* lB0 = Bs + (size_t)wb*8;
  bf16* lB1 = Bs + (size_t)(wb+256)*8;

  f32x4 acc[4][4];
  #pragma unroll
  for (int mi=0; mi<4; ++mi)
    #pragma unroll
    for (int ni=0; ni<4; ++ni)
      acc[mi][ni] = (f32x4){0.f,0.f,0.f,0.f};

  for (int k0 = 0; k0 < DMODEL; k0 += BK) {
    __syncthreads();
    gload16(X    + gA0 + k0, lA0);
    gload16(X    + gA1 + k0, lA1);
    gload16(Wcat + gB0 + k0, lB0);
    gload16(Wcat + gB1 + k0, lB1);
    __syncthreads();

    bf16x8 af[4], bfr[4];
    #pragma unroll
    for (int mi=0; mi<4; ++mi)
      af[mi] = *(const bf16x8*)&As[(wr + mi*16 + lr)*BK + lg*8];
    #pragma unroll
    for (int ni=0; ni<4; ++ni)
      bfr[ni] = *(const bf16x8*)&Bs[(wc + ni*16 + lr)*BK + lg*8];

    #pragma unroll
    for (int mi=0; mi<4; ++mi)
      #pragma unroll
      for (int ni=0; ni<4; ++ni)
        acc[mi][ni] = __builtin_amdgcn_mfma_f32_16x16x32_bf16(af[mi], bfr[ni], acc[mi][ni], 0, 0, 0);
  }

  const float* bias = (wsel==0) ? bq : ((wsel==1) ? bk : bv);
  bf16* Out = (wsel==0) ? Qo : ((wsel==1) ? Ko : Vo);
  const float oscale = (wsel==0) ? QSCALE : 1.0f;

  #pragma unroll
  for (int ni=0; ni<4; ++ni) {
    const int co = coln + wc + ni*16 + lr;
    const float bias_v = bias[co];
    const int h  = co >> 6;
    const int dh = co & 63;
    #pragma unroll
    for (int mi=0; mi<4; ++mi) {
      #pragma unroll
      for (int p=0; p<4; ++p) {
        const int gr = row0 + wr + mi*16 + lg*4 + p;
        const int s_ = gr >> 2;
        const int b_ = gr & 3;
        Out[((size_t)(b_*NHEAD + h)*S_LEN + s_)*DHEAD + dh] = (bf16)((acc[mi][ni][p] + bias_v) * oscale);
      }
    }
  }
}

// ---------------- MFMA flash attention: swapped QK^T, in-register P ----------------
// 4 waves, 32 q-rows/wave (2 subtiles of 16), QBLK=128. K/V double-buffered.
// Mask folded into V (rows scaled 0/1); lsum via ones*M01 rows 64..79 of Vt.
// t-relabeling rho(s) = s ^ ((s&16)>>2) applied to V/ones staging (absorbs the
// half-swap left by the 8-shfl P redistribution).
#define LPAD 72
#define QBLK 128

__global__ __launch_bounds__(256, 2) void attn_mfma(
    const bf16* __restrict__ Q, const bf16* __restrict__ K, const bf16* __restrict__ V,
    const float* __restrict__ mask, float* __restrict__ out)
{
  __shared__ __align__(16) bf16 KsBuf[2][64*LPAD];   // 18432 B
  __shared__ __align__(16) bf16 VtBuf[2][80*LPAD];   // 23040 B (V^T + ones*M01 rows 64..79)

  const int bh   = blockIdx.x;
  const int b_   = bh >> 4;
  const int h    = bh & 15;
  const int tid  = threadIdx.x;
  const int wv   = tid >> 6;             // 0..3
  const int lane = tid & 63;
  const int lg   = lane >> 4;            // 0..3
  const int lr   = lane & 15;
  const int q0   = blockIdx.y * QBLK;

  // ---- Q fragments (B-operand of swapped QK^T), 2 subtiles of 16 q-rows ----
  bf16x8 qa[2][2];
  #pragma unroll
  for (int st=0; st<2; ++st) {
    const bf16* Qp = Q + ((size_t)bh*S_LEN + q0 + wv*32 + st*16 + lr)*DHEAD;
    qa[st][0] = *(const bf16x8*)&Qp[lg*8];
    qa[st][1] = *(const bf16x8*)&Qp[32 + lg*8];
  }

  const bf16*  Kb = K + (size_t)bh*S_LEN*DHEAD;
  const bf16*  Vb = V + (size_t)bh*S_LEN*DHEAD;
  const float* mb = mask + (size_t)b_*S_LEN;

  // staging maps (256 threads)
  const int kr = tid >> 2,  kc = (tid & 3) << 4;          // K: 64 rows x 64, 2x16B/thread
  const int vr = tid & 63,  vc = (tid >> 6) << 4;         // V: row=lane, 16 cols/thread
  const int vrs = vr ^ ((vr & 16) >> 2);                  // rho(vr)
  const int orow = 64 + (tid >> 4);                       // ones rows 64..79
  const int ocol = (tid & 15) << 2;                       // 4 slots/thread
  const int omsk = ocol ^ ((ocol & 16) >> 2);             // rho(ocol) (group of 4 moves together)

  // ---- prologue: stage tile 0 ----
  bf16x8 kreg0 = *(const bf16x8*)&Kb[(size_t)kr*DHEAD + kc];
  bf16x8 kreg1 = *(const bf16x8*)&Kb[(size_t)kr*DHEAD + kc + 8];
  bf16x8 vreg0 = *(const bf16x8*)&Vb[(size_t)vr*DHEAD + vc];
  bf16x8 vreg1 = *(const bf16x8*)&Vb[(size_t)vr*DHEAD + vc + 8];
  float4 m4 = *(const float4*)&mb[omsk];
  float  vm = (mb[vr] < -1000.f) ? 0.f : 1.f;             // this V-row's 0/1 mask
  {
    bf16* Kn = (bf16*)KsBuf[0];
    bf16* Vn = (bf16*)VtBuf[0];
    *(bf16x8*)&Kn[kr*LPAD + kc]     = kreg0;
    *(bf16x8*)&Kn[kr*LPAD + kc + 8] = kreg1;
    #pragma unroll
    for (int i=0;i<8;++i){ Vn[(vc+i)*LPAD + vrs]   = (bf16)((float)vreg0[i]*vm);
                           Vn[(vc+8+i)*LPAD + vrs] = (bf16)((float)vreg1[i]*vm); }
    bf16x4 o4;
    o4[0] = (m4.x < -1000.f) ? (bf16)0.f : (bf16)1.f;
    o4[1] = (m4.y < -1000.f) ? (bf16)0.f : (bf16)1.f;
    o4[2] = (m4.z < -1000.f) ? (bf16)0.f : (bf16)1.f;
    o4[3] = (m4.w < -1000.f) ? (bf16)0.f : (bf16)1.f;
    *(bf16x4*)&Vn[orow*LPAD + ocol] = o4;
  }
  __syncthreads();

  // ctx[st][0..3] = output d-tiles; ctx[st][4] = masked row-sum (lsum)
  f32x4 ctx[2][5];
  #pragma unroll
  for (int st=0; st<2; ++st)
    #pragma unroll
    for (int nt=0; nt<5; ++nt) ctx[st][nt] = (f32x4){0.f,0.f,0.f,0.f};

  const int w_s = lg & 1;    // src-role low bit
  const int u_d = lg >> 1;   // dst-role high bit

  for (int t = 0; t < 16; ++t) {
    const bf16* Kc = KsBuf[t & 1];
    const bf16* Vc = VtBuf[t & 1];

    if (t < 15) {
      const size_t nb = (size_t)(t+1)*64;
      kreg0 = *(const bf16x8*)&Kb[(nb+kr)*DHEAD + kc];
      kreg1 = *(const bf16x8*)&Kb[(nb+kr)*DHEAD + kc + 8];
      vreg0 = *(const bf16x8*)&Vb[(nb+vr)*DHEAD + vc];
      vreg1 = *(const bf16x8*)&Vb[(nb+vr)*DHEAD + vc + 8];
      m4 = *(const float4*)&mb[nb + omsk];
      vm = (mb[nb + vr] < -1000.f) ? 0.f : 1.f;
    }

    #pragma unroll
    for (int st=0; st<2; ++st) {
      // ---- QK^T (swapped): D[t][q], lane holds q=lr, t = 16nt+4lg+p ----
      f32x4 sacc[4];
      __builtin_amdgcn_s_setprio(1);
      #pragma unroll
      for (int nt=0; nt<4; ++nt) {
        sacc[nt] = (f32x4){0.f,0.f,0.f,0.f};
        bf16x8 kb0 = *(const bf16x8*)&Kc[(nt*16 + lr)*LPAD + lg*8];
        bf16x8 kb1 = *(const bf16x8*)&Kc[(nt*16 + lr)*LPAD + 32 + lg*8];
        sacc[nt] = __builtin_amdgcn_mfma_f32_16x16x32_bf16(kb0, qa[st][0], sacc[nt], 0,0,0);
        sacc[nt] = __builtin_amdgcn_mfma_f32_16x16x32_bf16(kb1, qa[st][1], sacc[nt], 0,0,0);
      }
      __builtin_amdgcn_s_setprio(0);

      // ---- softmax numerator (no mask add: mask folded into V) ----
      int dwi[4][2];
      #pragma unroll
      for (int nt=0; nt<4; ++nt) {
        float e0 = fast_exp2(sacc[nt][0]);
        float e1 = fast_exp2(sacc[nt][1]);
        float e2 = fast_exp2(sacc[nt][2]);
        float e3 = fast_exp2(sacc[nt][3]);
        dwi[nt][0] = pack_bf16(e0, e1);
        dwi[nt][1] = pack_bf16(e2, e3);
      }

      // ---- redistribute D-layout -> A-frag layout: 8 shfls ----
      int pad0[4], pad1[4];
      #pragma unroll
      for (int b=0; b<2; ++b)
        #pragma unroll
        for (int c=0; c<2; ++c)
          #pragma unroll
          for (int a=0; a<2; ++a) {
            const int x  = c ^ w_s;
            const int tv = x ? dwi[2*b+1][a] : dwi[2*b][a];
            const int sl = lr + 16*(2*w_s + (c ^ u_d));   // note: dst v = lg&1 = w_s
            const int rv = __shfl(tv, sl, 64);
            if (b == 0) pad0[2*c + a] = rv; else pad1[2*c + a] = rv;
          }
      union { int i[4]; bf16x8 v; } ua, ub;
      ua.i[0]=pad0[0]; ua.i[1]=pad0[1]; ua.i[2]=pad0[2]; ua.i[3]=pad0[3];
      ub.i[0]=pad1[0]; ub.i[1]=pad1[1]; ub.i[2]=pad1[2]; ub.i[3]=pad1[3];

      // ---- PV + lsum (5th tile = ones*M01 rows) ----
      __builtin_amdgcn_s_setprio(1);
      #pragma unroll
      for (int nt=0; nt<5; ++nt) {
        bf16x8 vb0 = *(const bf16x8*)&Vc[(nt*16 + lr)*LPAD + lg*8];
        bf16x8 vb1 = *(const bf16x8*)&Vc[(nt*16 + lr)*LPAD + 32 + lg*8];
        ctx[st][nt] = __builtin_amdgcn_mfma_f32_16x16x32_bf16(ua.v, vb0, ctx[st][nt], 0,0,0);
        ctx[st][nt] = __builtin_amdgcn_mfma_f32_16x16x32_bf16(ub.v, vb1, ctx[st][nt], 0,0,0);
      }
      __builtin_amdgcn_s_setprio(0);
    }

    // ---- stage next tile into the other buffer ----
    if (t < 15) {
      bf16* Kn = (bf16*)KsBuf[(t+1) & 1];
      bf16* Vn = (bf16*)VtBuf[(t+1) & 1];
      *(bf16x8*)&Kn[kr*LPAD + kc]     = kreg0;
      *(bf16x8*)&Kn[kr*LPAD + kc + 8] = kreg1;
      #pragma unroll
      for (int i=0;i<8;++i){ Vn[(vc+i)*LPAD + vrs]   = (bf16)((float)vreg0[i]*vm);
                             Vn[(vc+8+i)*LPAD + vrs] = (bf16)((float)vreg1[i]*vm); }
      bf16x4 o4;
      o4[0] = (m4.x < -1000.f) ? (bf16)0.f : (bf16)1.f;
      o4[1] = (m4.y < -1000.f) ? (bf16)0.f : (bf16)1.f;
      o4[2] = (m4.z < -1000.f) ? (bf16)0.f : (bf16)1.f;
      o4[3] = (m4.w < -1000.f) ? (bf16)0.f : (bf16)1.f;
      *(bf16x4*)&Vn[orow*LPAD + ocol] = o4;
    }
    __syncthreads();
  }

  // ---- write out: out[s][b][h*64 + d]; lsum = ctx[st][4][p] on every lane ----
  #pragma unroll
  for (int st=0; st<2; ++st) {
    #pragma unroll
    for (int p=0; p<4; ++p) {
      const float inv = 1.f / ctx[st][4][p];
      const int qg = q0 + wv*32 + st*16 + lg*4 + p;
      float* op = out + ((size_t)qg*BATCH + b_)*DMODEL + h*DHEAD;
      #pragma unroll
      for (int nt=0; nt<4; ++nt) op[nt*16 + lr] = ctx[st][nt][p] * inv;
    }
  }
}

// ---------------- launch ----------------
extern "C" void kernel_launch(void* const* d_in, const int* in_sizes, int n_in,
                              void* d_out, int out_size, void* d_ws, size_t ws_size,
                              hipStream_t stream) {
  const float* hs   = (const float*)d_in[0];
  const float* mask = (const float*)d_in[1];
  const float* Wq   = (const float*)d_in[2];
  const float* bq   = (const float*)d_in[3];
  const float* Wk   = (const float*)d_in[4];
  const float* bk   = (const float*)d_in[5];
  const float* Wv   = (const float*)d_in[6];
  const float* bv   = (const float*)d_in[7];
  float* out = (float*)d_out;

  char* ws = (char*)d_ws;
  bf16* Xb = (bf16*)ws;
  bf16* Wb = Xb + (size_t)NROWS*DMODEL;
  bf16* Qw = Wb + (size_t)3*DMODEL*DMODEL;
  bf16* Kw = Qw + (size_t)NROWS*DMODEL;
  bf16* Vw = Kw + (size_t)NROWS*DMODEL;

  cvt_all<<<3584, 256, 0, stream>>>(hs, Wq, Wk, Wv, Xb, Wb);

  qkv_gemm<<<dim3(NROWS/BM, 3*DMODEL/BN), 256, 0, stream>>>(Xb, Wb, bq, bk, bv, Qw, Kw, Vw);

  attn_mfma<<<dim3(BATCH*NHEAD, S_LEN/QBLK), 256, 0, stream>>>(Qw, Kw, Vw, mask, out);
}

// Round 7
// 71.434 us; speedup vs baseline: 1.1177x; 1.1177x over previous
//
#include <hip/hip_runtime.h>
#include <hip/hip_bf16.h>

#define S_LEN  1024
#define BATCH  4
#define DMODEL 1024
#define NHEAD  16
#define DHEAD  64
#define NROWS  (S_LEN*BATCH)   // 4096

typedef __bf16 bf16;
typedef __bf16 bf16x2 __attribute__((ext_vector_type(2)));
typedef __bf16 bf16x4 __attribute__((ext_vector_type(4)));
typedef __bf16 bf16x8 __attribute__((ext_vector_type(8)));
typedef float  f32x4  __attribute__((ext_vector_type(4)));
typedef float  f32x16 __attribute__((ext_vector_type(16)));

#define AS1 __attribute__((address_space(1)))
#define AS3 __attribute__((address_space(3)))

#define QSCALE  0.18033688011112042f   // 0.125 * log2(e)

__device__ __forceinline__ void gload16(const bf16* g, bf16* l) {
  __builtin_amdgcn_global_load_lds((const AS1 void*)g, (AS3 void*)l, 16, 0, 0);
}

__device__ __forceinline__ float fast_exp2(float x) {
#if __has_builtin(__builtin_amdgcn_exp2f)
  return __builtin_amdgcn_exp2f(x);
#else
  return exp2f(x);
#endif
}

// ---------------- fused fp32 -> bf16 convert ----------------
__global__ __launch_bounds__(256) void cvt_all(
    const float* __restrict__ hs, const float* __restrict__ wq,
    const float* __restrict__ wk, const float* __restrict__ wv,
    bf16* __restrict__ Xb, bf16* __restrict__ Wb)
{
  const int b = blockIdx.x;
  const float* src; bf16* dst; int i;
  if (b < 2048)      { src = hs; dst = Xb;                           i = b*256        + threadIdx.x; }
  else if (b < 2560) { src = wq; dst = Wb;                           i = (b-2048)*256 + threadIdx.x; }
  else if (b < 3072) { src = wk; dst = Wb + (size_t)DMODEL*DMODEL;   i = (b-2560)*256 + threadIdx.x; }
  else               { src = wv; dst = Wb + (size_t)2*DMODEL*DMODEL; i = (b-3072)*256 + threadIdx.x; }
  const float4* s4 = (const float4*)src;
  float4 a = s4[2*i], c = s4[2*i+1];
  bf16x8 o;
  o[0]=(bf16)a.x; o[1]=(bf16)a.y; o[2]=(bf16)a.z; o[3]=(bf16)a.w;
  o[4]=(bf16)c.x; o[5]=(bf16)c.y; o[6]=(bf16)c.z; o[7]=(bf16)c.w;
  ((bf16x8*)dst)[i] = o;
}

// ---------------- fused QKV GEMM, m97 structure (unchanged) ----------------
#define BM 128
#define BN 128
#define BK 32

__global__ __launch_bounds__(256) void qkv_gemm(
    const bf16* __restrict__ X, const bf16* __restrict__ Wcat,
    const float* __restrict__ bq, const float* __restrict__ bk, const float* __restrict__ bv,
    bf16* __restrict__ Qo, bf16* __restrict__ Ko, bf16* __restrict__ Vo)
{
  __shared__ __align__(16) bf16 As[BM*BK];
  __shared__ __align__(16) bf16 Bs[BN*BK];

  const int tid  = threadIdx.x;
  const int row0 = blockIdx.x * BM;
  const int col0 = blockIdx.y * BN;
  const int wsel = col0 >> 10;
  const int coln = col0 & 1023;

  const int wv   = tid >> 6;
  const int lane = tid & 63;
  const int lg   = lane >> 4;
  const int lr   = lane & 15;
  const int wr   = (wv >> 1) << 6;
  const int wc   = (wv & 1) << 6;

  const int c0 = tid, c1 = tid + 256;
  const size_t gA0 = (size_t)(row0 + (c0>>2))*DMODEL + (size_t)((c0&3)<<3);
  const size_t gA1 = (size_t)(row0 + (c1>>2))*DMODEL + (size_t)((c1&3)<<3);
  const size_t gB0 = (size_t)(col0 + (c0>>2))*DMODEL + (size_t)((c0&3)<<3);
  const size_t gB1 = (size_t)(col0 + (c1>>2))*DMODEL + (size_t)((c1&3)<<3);
  const int wb = (tid >> 6) << 6;
  bf16* lA0 = As + (size_t)wb*8;
  bf16* lA1 = As + (size_t)(wb+256)*8;
  bf16* lB0 = Bs + (size_t)wb*8;
  bf16* lB1 = Bs + (size_t)(wb+256)*8;

  f32x4 acc[4][4];
  #pragma unroll
  for (int mi=0; mi<4; ++mi)
    #pragma unroll
    for (int ni=0; ni<4; ++ni)
      acc[mi][ni] = (f32x4){0.f,0.f,0.f,0.f};

  for (int k0 = 0; k0 < DMODEL; k0 += BK) {
    __syncthreads();
    gload16(X    + gA0 + k0, lA0);
    gload16(X    + gA1 + k0, lA1);
    gload16(Wcat + gB0 + k0, lB0);
    gload16(Wcat + gB1 + k0, lB1);
    __syncthreads();

    bf16x8 af[4], bfr[4];
    #pragma unroll
    for (int mi=0; mi<4; ++mi)
      af[mi] = *(const bf16x8*)&As[(wr + mi*16 + lr)*BK + lg*8];
    #pragma unroll
    for (int ni=0; ni<4; ++ni)
      bfr[ni] = *(const bf16x8*)&Bs[(wc + ni*16 + lr)*BK + lg*8];

    #pragma unroll
    for (int mi=0; mi<4; ++mi)
      #pragma unroll
      for (int ni=0; ni<4; ++ni)
        acc[mi][ni] = __builtin_amdgcn_mfma_f32_16x16x32_bf16(af[mi], bfr[ni], acc[mi][ni], 0, 0, 0);
  }

  const float* bias = (wsel==0) ? bq : ((wsel==1) ? bk : bv);
  bf16* Out = (wsel==0) ? Qo : ((wsel==1) ? Ko : Vo);
  const float oscale = (wsel==0) ? QSCALE : 1.0f;

  #pragma unroll
  for (int ni=0; ni<4; ++ni) {
    const int co = coln + wc + ni*16 + lr;
    const float bias_v = bias[co];
    const int h  = co >> 6;
    const int dh = co & 63;
    #pragma unroll
    for (int mi=0; mi<4; ++mi) {
      #pragma unroll
      for (int p=0; p<4; ++p) {
        const int gr = row0 + wr + mi*16 + lg*4 + p;
        const int s_ = gr >> 2;
        const int b_ = gr & 3;
        Out[((size_t)(b_*NHEAD + h)*S_LEN + s_)*DHEAD + dh] = (bf16)((acc[mi][ni][p] + bias_v) * oscale);
      }
    }
  }
}

// ---------------- MFMA flash attention: 32x32 MFMA, zero-shuffle P ----------------
// 4 waves x 32 q-rows, QBLK=128, dbuf K/V, XOR chunk-swizzle (chunk ^= row&7).
// Swapped QK^T: D[t][q], q=lane&31. PV A-frag slot->t map == the t-set each lane
// already holds, so P needs NO cross-lane movement; V^T B-frags are read with the
// same map (2x ds_read_b64 per frag). Mask additive in f32 LDS (exp2 underflow->0).
#define QBLK 128
// swizzled elem index of 16B-chunk base within a 64-elem row
#define LSW(row, chunk) (((row)<<6) + ((((chunk) ^ ((row)&7)))<<3))

__global__ __launch_bounds__(256, 2) void attn_mfma(
    const bf16* __restrict__ Q, const bf16* __restrict__ K, const bf16* __restrict__ V,
    const float* __restrict__ mask, float* __restrict__ out)
{
  __shared__ __align__(16) bf16 Ks[2][64*64];   // 16 KB
  __shared__ __align__(16) bf16 Vt[2][64*64];   // 16 KB (V^T, swizzled)
  __shared__ float Mskf[S_LEN];                 //  4 KB
  __shared__ float Linv[4][32];                 // 512 B

  const int bh   = blockIdx.x;
  const int b_   = bh >> 4;
  const int h_   = bh & 15;
  const int tid  = threadIdx.x;
  const int wv   = tid >> 6;             // 0..3
  const int lane = tid & 63;
  const int l31  = lane & 31;
  const int hh   = lane >> 5;            // 0/1
  const int q0   = blockIdx.y * QBLK;

  // ---- stage mask row (raw f32; -1e4 additive underflows exp2 to 0) ----
  *(float4*)&Mskf[tid*4] = *(const float4*)&mask[(size_t)b_*S_LEN + tid*4];

  // ---- Q B-frags from global (pre-scaled by QSCALE in gemm): q = lane&31 ----
  const bf16* Qp = Q + ((size_t)bh*S_LEN + q0 + wv*32 + l31)*DHEAD;
  bf16x8 qb[4];
  #pragma unroll
  for (int dk=0; dk<4; ++dk) qb[dk] = *(const bf16x8*)&Qp[dk*16 + hh*8];

  const bf16* Kb = K + (size_t)bh*S_LEN*DHEAD;
  const bf16* Vb = V + (size_t)bh*S_LEN*DHEAD;

  // staging maps (256 threads)
  const int krow = tid >> 2, kch = tid & 3;   // K: row, chunks kch & kch+4
  const int vrow = tid & 63, vcb = tid >> 6;  // V: row=lane, 16 cols starting vcb*16

  // ---- prologue: stage tile 0 ----
  bf16x8 kr0 = *(const bf16x8*)&Kb[(size_t)krow*DHEAD + kch*8];
  bf16x8 kr1 = *(const bf16x8*)&Kb[(size_t)krow*DHEAD + kch*8 + 32];
  bf16x8 vr0 = *(const bf16x8*)&Vb[(size_t)vrow*DHEAD + vcb*16];
  bf16x8 vr1 = *(const bf16x8*)&Vb[(size_t)vrow*DHEAD + vcb*16 + 8];
  {
    *(bf16x8*)&Ks[0][LSW(krow, kch)]   = kr0;
    *(bf16x8*)&Ks[0][LSW(krow, kch+4)] = kr1;
    #pragma unroll
    for (int i=0;i<8;++i) {
      const int d0 = vcb*16 + i, d1 = d0 + 8;
      Vt[0][(d0<<6) + (((vrow>>3) ^ (d0&7))<<3) + (vrow&7)] = vr0[i];
      Vt[0][(d1<<6) + (((vrow>>3) ^ (d1&7))<<3) + (vrow&7)] = vr1[i];
    }
  }
  __syncthreads();

  f32x16 ctx[2];
  ctx[0] = (f32x16)0.f; ctx[1] = (f32x16)0.f;
  float lsum = 0.f;

  for (int t = 0; t < 16; ++t) {
    const bf16* Kc = Ks[t & 1];
    const bf16* Vc = Vt[t & 1];

    // issue next tile's global loads early
    if (t < 15) {
      const size_t nb = (size_t)(t+1)*64;
      kr0 = *(const bf16x8*)&Kb[(nb+krow)*DHEAD + kch*8];
      kr1 = *(const bf16x8*)&Kb[(nb+krow)*DHEAD + kch*8 + 32];
      vr0 = *(const bf16x8*)&Vb[(nb+vrow)*DHEAD + vcb*16];
      vr1 = *(const bf16x8*)&Vb[(nb+vrow)*DHEAD + vcb*16 + 8];
    }

    // ---- QK^T (swapped): D[t][q], 2 t-tiles of 32, contraction dh=64 ----
    f32x16 sacc[2];
    sacc[0] = (f32x16)0.f; sacc[1] = (f32x16)0.f;
    __builtin_amdgcn_s_setprio(1);
    #pragma unroll
    for (int tt=0; tt<2; ++tt) {
      const int row = tt*32 + l31;
      #pragma unroll
      for (int dk=0; dk<4; ++dk) {
        bf16x8 ka = *(const bf16x8*)&Kc[LSW(row, dk*2 + hh)];
        sacc[tt] = __builtin_amdgcn_mfma_f32_32x32x16_bf16(ka, qb[dk], sacc[tt], 0,0,0);
      }
    }
    __builtin_amdgcn_s_setprio(0);

    // ---- softmax: p = exp2(s + m); lsum VALU; pack to PV A-frags in-lane ----
    const int tb = t*64;
    bf16x8 pf[2][2];
    #pragma unroll
    for (int tt=0; tt<2; ++tt) {
      f32x4 mv[4];
      #pragma unroll
      for (int g=0; g<4; ++g)
        mv[g] = *(const f32x4*)&Mskf[tb + tt*32 + 8*g + 4*hh];
      float pe[16];
      #pragma unroll
      for (int e=0; e<16; ++e) {
        pe[e] = fast_exp2(sacc[tt][e] + mv[e>>2][e&3]);
        lsum += pe[e];
      }
      union { bf16x2 h2[8]; bf16x8 v[2]; } u;
      #pragma unroll
      for (int j=0; j<8; ++j) { bf16x2 p2; p2[0]=(bf16)pe[2*j]; p2[1]=(bf16)pe[2*j+1]; u.h2[j]=p2; }
      pf[tt][0] = u.v[0]; pf[tt][1] = u.v[1];
    }

    // ---- PV: O[q][d] += P * V ; B-frags via slot->t map (2x b64 each) ----
    __builtin_amdgcn_s_setprio(1);
    #pragma unroll
    for (int nt=0; nt<2; ++nt) {
      const int drow = nt*32 + l31;
      const int dbase = (drow<<6) + 4*hh;
      const int dsw = (drow&7);
      #pragma unroll
      for (int tt=0; tt<2; ++tt) {
        #pragma unroll
        for (int kk=0; kk<2; ++kk) {
          const int lc = tt*4 + kk*2;
          bf16x4 lo = *(const bf16x4*)&Vc[dbase + (((lc  ) ^ dsw)<<3)];
          bf16x4 hi = *(const bf16x4*)&Vc[dbase + (((lc+1) ^ dsw)<<3)];
          bf16x8 vb;
          #pragma unroll
          for (int j=0; j<4; ++j) { vb[j]=lo[j]; vb[4+j]=hi[j]; }
          ctx[nt] = __builtin_amdgcn_mfma_f32_32x32x16_bf16(pf[tt][kk], vb, ctx[nt], 0,0,0);
        }
      }
    }
    __builtin_amdgcn_s_setprio(0);

    // ---- stage next tile into other buffer ----
    if (t < 15) {
      bf16* Kn = (bf16*)Ks[(t+1) & 1];
      bf16* Vn = (bf16*)Vt[(t+1) & 1];
      *(bf16x8*)&Kn[LSW(krow, kch)]   = kr0;
      *(bf16x8*)&Kn[LSW(krow, kch+4)] = kr1;
      #pragma unroll
      for (int i=0;i<8;++i) {
        const int d0 = vcb*16 + i, d1 = d0 + 8;
        Vn[(d0<<6) + (((vrow>>3) ^ (d0&7))<<3) + (vrow&7)] = vr0[i];
        Vn[(d1<<6) + (((vrow>>3) ^ (d1&7))<<3) + (vrow&7)] = vr1[i];
      }
    }
    __syncthreads();
  }

  // ---- lsum: partner-half add, distribute 1/lsum via per-wave LDS row ----
  const float tot = lsum + __shfl_xor(lsum, 32);
  if (lane < 32) Linv[wv][l31] = 1.f / tot;
  f32x4 inv4[4];
  #pragma unroll
  for (int g=0; g<4; ++g) inv4[g] = *(const f32x4*)&Linv[wv][8*g + 4*hh];

  // ---- write out: out[qg][b][h*64 + nt*32 + (lane&31)] ----
  float* op = out + ((size_t)(q0 + wv*32)*BATCH + b_)*DMODEL + h_*DHEAD + l31;
  #pragma unroll
  for (int e=0; e<16; ++e) {
    const int qe = (e&3) + 8*(e>>2) + 4*hh;
    const float inv = inv4[e>>2][e&3];
    float* oq = op + (size_t)qe*BATCH*DMODEL;
    oq[0]  = ctx[0][e] * inv;
    oq[32] = ctx[1][e] * inv;
  }
}

// ---------------- launch ----------------
extern "C" void kernel_launch(void* const* d_in, const int* in_sizes, int n_in,
                              void* d_out, int out_size, void* d_ws, size_t ws_size,
                              hipStream_t stream) {
  const float* hs   = (const float*)d_in[0];
  const float* mask = (const float*)d_in[1];
  const float* Wq   = (const float*)d_in[2];
  const float* bq   = (const float*)d_in[3];
  const float* Wk   = (const float*)d_in[4];
  const float* bk   = (const float*)d_in[5];
  const float* Wv   = (const float*)d_in[6];
  const float* bv   = (const float*)d_in[7];
  float* out = (float*)d_out;

  char* ws = (char*)d_ws;
  bf16* Xb = (bf16*)ws;
  bf16* Wb = Xb + (size_t)NROWS*DMODEL;
  bf16* Qw = Wb + (size_t)3*DMODEL*DMODEL;
  bf16* Kw = Qw + (size_t)NROWS*DMODEL;
  bf16* Vw = Kw + (size_t)NROWS*DMODEL;

  cvt_all<<<3584, 256, 0, stream>>>(hs, Wq, Wk, Wv, Xb, Wb);

  qkv_gemm<<<dim3(NROWS/BM, 3*DMODEL/BN), 256, 0, stream>>>(Xb, Wb, bq, bk, bv, Qw, Kw, Vw);

  attn_mfma<<<dim3(BATCH*NHEAD, S_LEN/QBLK), 256, 0, stream>>>(Qw, Kw, Vw, mask, out);
}